// Round 1
// baseline (7490.328 us; speedup 1.0000x reference)
//
#include <hip/hip_runtime.h>
#include <hip/hip_bf16.h>

namespace {
constexpr int BATCH = 256;
constexpr int TENC  = 64;
constexpr int HID   = 1024;
constexpr int VOC   = 128;
constexpr int LDEC  = 32;
constexpr int G4    = 4 * HID;  // 4096
}

// ---------------------------------------------------------------------------
// init: zero h0, c; tok = delimiter (V-1)
// grid: (BATCH*HID)/256 = 1024 blocks x 256
// ---------------------------------------------------------------------------
__global__ __launch_bounds__(256) void k_init(float* __restrict__ h0,
                                              float* __restrict__ c,
                                              int* __restrict__ tok) {
  int i = blockIdx.x * 256 + threadIdx.x;
  h0[i] = 0.f;
  c[i]  = 0.f;
  if (i < BATCH) tok[i] = VOC - 1;
}

// ---------------------------------------------------------------------------
// Precompute P[v][col] = emb[v] @ W[:,col] + b[col]   (V x 4H), for enc & dec.
// M=128(all rows) x N=64-col tile, BK=32, 256 threads, thread = 8r x 4c.
// grid: (G4/64, 2)
// ---------------------------------------------------------------------------
__global__ __launch_bounds__(256) void k_precompute(
    const float* __restrict__ enc_emb, const float* __restrict__ enc_W,
    const float* __restrict__ enc_b,   const float* __restrict__ dec_emb,
    const float* __restrict__ dec_W,   const float* __restrict__ dec_b,
    float* __restrict__ P_enc, float* __restrict__ P_dec) {
  const float* emb;
  const float* W;
  const float* bias;
  float* P;
  if (blockIdx.y == 0) { emb = enc_emb; W = enc_W; bias = enc_b; P = P_enc; }
  else                 { emb = dec_emb; W = dec_W; bias = dec_b; P = P_dec; }

  __shared__ float A_s[32][132];  // [k][v]  (transposed emb tile, padded)
  __shared__ float B_s[32][68];   // [k][col]

  const int t    = threadIdx.x;
  const int col0 = blockIdx.x * 64;
  const int tx   = t % 16;  // 4-col group
  const int ty   = t / 16;  // 8-row group

  float acc[8][4];
#pragma unroll
  for (int i = 0; i < 8; ++i)
#pragma unroll
    for (int j = 0; j < 4; ++j) acc[i][j] = 0.f;

  for (int k0 = 0; k0 < HID; k0 += 32) {
    __syncthreads();
    // stage emb tile (128 rows x 32 k), transposed into A_s
#pragma unroll
    for (int i = 0; i < 4; ++i) {
      int idx = t + i * 256;          // 0..1023 quad index
      int v   = idx >> 3;             // 0..127
      int kq  = (idx & 7) * 4;        // 0..28
      const float4 val = *(const float4*)&emb[v * HID + k0 + kq];
      A_s[kq + 0][v] = val.x;
      A_s[kq + 1][v] = val.y;
      A_s[kq + 2][v] = val.z;
      A_s[kq + 3][v] = val.w;
    }
    // stage W tile (32 k x 64 cols)
#pragma unroll
    for (int i = 0; i < 2; ++i) {
      int idx = t + i * 256;          // 0..511
      int kk  = idx >> 4;             // 0..31
      int cq  = (idx & 15) * 4;       // 0..60
      *(float4*)&B_s[kk][cq] = *(const float4*)&W[(k0 + kk) * G4 + col0 + cq];
    }
    __syncthreads();
#pragma unroll
    for (int kk = 0; kk < 32; ++kk) {
      const float4 a0 = *(const float4*)&A_s[kk][ty * 8];
      const float4 a1 = *(const float4*)&A_s[kk][ty * 8 + 4];
      const float4 b  = *(const float4*)&B_s[kk][tx * 4];
      const float av[8] = {a0.x, a0.y, a0.z, a0.w, a1.x, a1.y, a1.z, a1.w};
      const float bv[4] = {b.x, b.y, b.z, b.w};
#pragma unroll
      for (int i = 0; i < 8; ++i)
#pragma unroll
        for (int j = 0; j < 4; ++j) acc[i][j] += av[i] * bv[j];
    }
  }

  const float4 b4 = *(const float4*)&bias[col0 + tx * 4];
#pragma unroll
  for (int i = 0; i < 8; ++i) {
    const int vrow = ty * 8 + i;
    float4 o;
    o.x = acc[i][0] + b4.x;
    o.y = acc[i][1] + b4.y;
    o.z = acc[i][2] + b4.z;
    o.w = acc[i][3] + b4.w;
    *(float4*)&P[vrow * G4 + col0 + tx * 4] = o;
  }
}

// ---------------------------------------------------------------------------
// One LSTM step, fused GEMM (h_in @ U) + gates + mask.
// Tile: 32 batch rows x 32 hidden cols (x4 gates), BK=32, 256 threads.
// thread = 4 rows x 1 col x 4 gates. grid: 256 blocks (1/CU),
// blockIdx%8 == coltile%8 -> XCD-pinned U slices (L2-resident, 2MB/XCD).
// ---------------------------------------------------------------------------
__global__ __launch_bounds__(256) void k_cell(
    const float* __restrict__ h_in, float* __restrict__ h_out,
    float* __restrict__ c, const float* __restrict__ U,
    const float* __restrict__ P, const int* __restrict__ tok_idx,
    int tok_stride) {
  const int bx = blockIdx.x;
  const int ct = bx % 32;  // column tile (hidden)
  const int rt = bx / 32;  // row tile (batch)
  const int j0 = ct * 32;
  const int r0 = rt * 32;

  __shared__ float A_s[32][36];     // [k][row]   (transposed h tile)
  __shared__ float B_s[4][32][36];  // [gate][k][col]

  const int t  = threadIdx.x;
  const int tx = t % 32;  // col within tile
  const int ty = t / 32;  // row group (8 groups x 4 rows)

  float acc[4][4];  // [gate][row]
#pragma unroll
  for (int g = 0; g < 4; ++g)
#pragma unroll
    for (int r = 0; r < 4; ++r) acc[g][r] = 0.f;

  for (int k0 = 0; k0 < HID; k0 += 32) {
    __syncthreads();
    {  // stage h tile (32 rows x 32 k) transposed
      const int r  = t >> 3;
      const int kq = (t & 7) * 4;
      const float4 val = *(const float4*)&h_in[(r0 + r) * HID + k0 + kq];
      A_s[kq + 0][r] = val.x;
      A_s[kq + 1][r] = val.y;
      A_s[kq + 2][r] = val.z;
      A_s[kq + 3][r] = val.w;
    }
#pragma unroll
    for (int g = 0; g < 4; ++g) {  // stage U tile: 4 gate col-blocks
      const int kk = t >> 3;
      const int cq = (t & 7) * 4;
      *(float4*)&B_s[g][kk][cq] =
          *(const float4*)&U[(k0 + kk) * G4 + g * HID + j0 + cq];
    }
    __syncthreads();
#pragma unroll
    for (int kk = 0; kk < 32; ++kk) {
      const float4 a  = *(const float4*)&A_s[kk][ty * 4];
      const float b0  = B_s[0][kk][tx];
      const float b1  = B_s[1][kk][tx];
      const float b2  = B_s[2][kk][tx];
      const float b3  = B_s[3][kk][tx];
      acc[0][0] += a.x * b0; acc[0][1] += a.y * b0; acc[0][2] += a.z * b0; acc[0][3] += a.w * b0;
      acc[1][0] += a.x * b1; acc[1][1] += a.y * b1; acc[1][2] += a.z * b1; acc[1][3] += a.w * b1;
      acc[2][0] += a.x * b2; acc[2][1] += a.y * b2; acc[2][2] += a.z * b2; acc[2][3] += a.w * b2;
      acc[3][0] += a.x * b3; acc[3][1] += a.y * b3; acc[3][2] += a.z * b3; acc[3][3] += a.w * b3;
    }
  }

  const int col = j0 + tx;
#pragma unroll
  for (int r = 0; r < 4; ++r) {
    const int row   = r0 + ty * 4 + r;
    const int token = tok_idx[row * tok_stride];
    const float* Px = P + token * G4;
    const float zi = acc[0][r] + Px[col];
    const float zf = acc[1][r] + Px[HID + col];
    const float zg = acc[2][r] + Px[2 * HID + col];
    const float zo = acc[3][r] + Px[3 * HID + col];
    const float ig = 1.f / (1.f + expf(-zi));
    const float fg = 1.f / (1.f + expf(-zf));
    const float gg = tanhf(zg);
    const float og = 1.f / (1.f + expf(-zo));
    const float c_old = c[row * HID + col];
    const float c2 = fg * c_old + ig * gg;
    const float h2 = og * tanhf(c2);
    if (token != 0) {
      h_out[row * HID + col] = h2;
      c[row * HID + col]     = c2;
    } else {
      h_out[row * HID + col] = h_in[row * HID + col];
      // c unchanged
    }
  }
}

// ---------------------------------------------------------------------------
// Decoder output: logits = h @ out_W + out_b; softmax -> y; argmax -> tok.
// grid: BATCH/2 blocks x 128 threads (thread = one vocab col, 2 batch rows).
// ---------------------------------------------------------------------------
__global__ __launch_bounds__(128) void k_logits(
    const float* __restrict__ h, const float* __restrict__ out_W,
    const float* __restrict__ out_b, float* __restrict__ out, int t,
    int* __restrict__ tok) {
  const int b0 = blockIdx.x * 2;
  const int v  = threadIdx.x;

  __shared__ float h_s[2][HID];
  __shared__ float red_v[128];
  __shared__ int   red_i[128];

#pragma unroll
  for (int i = 0; i < 4; ++i) {     // 2*1024 floats / (128 thr * 4) = 4
    int q  = v + i * 128;           // quad index 0..511
    int r  = q >> 8;                // 0..1
    int kq = (q & 255) * 4;         // 0..1020
    *(float4*)&h_s[r][kq] = *(const float4*)&h[(b0 + r) * HID + kq];
  }
  __syncthreads();

  float acc[2];
  acc[0] = out_b[v];
  acc[1] = acc[0];
#pragma unroll 8
  for (int k = 0; k < HID; ++k) {
    const float w = out_W[k * VOC + v];
    acc[0] += h_s[0][k] * w;
    acc[1] += h_s[1][k] * w;
  }

  for (int r = 0; r < 2; ++r) {
    const int b = b0 + r;
    // max + first-argmax reduction
    red_v[v] = acc[r];
    red_i[v] = v;
    __syncthreads();
    for (int s = 64; s > 0; s >>= 1) {
      if (v < s) {
        const float ov = red_v[v + s];
        const int   oi = red_i[v + s];
        if (ov > red_v[v] || (ov == red_v[v] && oi < red_i[v])) {
          red_v[v] = ov;
          red_i[v] = oi;
        }
      }
      __syncthreads();
    }
    const float mx  = red_v[0];
    const int amax  = red_i[0];
    __syncthreads();
    const float e = expf(acc[r] - mx);
    red_v[v] = e;
    __syncthreads();
    for (int s = 64; s > 0; s >>= 1) {
      if (v < s) red_v[v] += red_v[v + s];
      __syncthreads();
    }
    const float sum = red_v[0];
    out[b * (LDEC * VOC) + t * VOC + v] = e / sum;
    if (v == 0) {
      tok[b] = amax;
      out[BATCH * LDEC * VOC + t * BATCH + b] = (float)amax;
    }
    __syncthreads();
  }
}

// ---------------------------------------------------------------------------
extern "C" void kernel_launch(void* const* d_in, const int* in_sizes, int n_in,
                              void* d_out, int out_size, void* d_ws,
                              size_t ws_size, hipStream_t stream) {
  (void)in_sizes; (void)n_in; (void)out_size; (void)ws_size;
  const int*   inputs  = (const int*)d_in[0];
  // d_in[1] = max_len (compile-time 32)
  const float* enc_emb = (const float*)d_in[2];
  const float* enc_W   = (const float*)d_in[3];
  const float* enc_U   = (const float*)d_in[4];
  const float* enc_b   = (const float*)d_in[5];
  const float* dec_emb = (const float*)d_in[6];
  const float* dec_W   = (const float*)d_in[7];
  const float* dec_U   = (const float*)d_in[8];
  const float* dec_b   = (const float*)d_in[9];
  const float* out_W   = (const float*)d_in[10];
  const float* out_b   = (const float*)d_in[11];
  float* out = (float*)d_out;

  float* ws    = (float*)d_ws;
  float* P_enc = ws;                       // V*4H
  float* P_dec = P_enc + VOC * G4;         // V*4H
  float* h0    = P_dec + VOC * G4;         // B*H
  float* h1    = h0 + BATCH * HID;         // B*H
  float* c     = h1 + BATCH * HID;         // B*H
  int*   tok   = (int*)(c + BATCH * HID);  // B

  k_init<<<(BATCH * HID) / 256, 256, 0, stream>>>(h0, c, tok);

  dim3 pgrid(G4 / 64, 2);
  k_precompute<<<pgrid, 256, 0, stream>>>(enc_emb, enc_W, enc_b, dec_emb,
                                          dec_W, dec_b, P_enc, P_dec);

  float* hin  = h0;
  float* hout = h1;
  for (int t = 0; t < TENC; ++t) {
    k_cell<<<256, 256, 0, stream>>>(hin, hout, c, enc_U, P_enc, inputs + t,
                                    TENC);
    float* tmp = hin; hin = hout; hout = tmp;
  }
  for (int s = 0; s < LDEC; ++s) {
    k_cell<<<256, 256, 0, stream>>>(hin, hout, c, dec_U, P_dec, tok, 1);
    k_logits<<<BATCH / 2, 128, 0, stream>>>(hout, out_W, out_b, out, s, tok);
    float* tmp = hin; hin = hout; hout = tmp;
  }
}